// Round 7
// baseline (405.794 us; speedup 1.0000x reference)
//
#include <hip/hip_runtime.h>

#define NSTEPS 64

typedef __attribute__((ext_vector_type(8))) short short8;   // 8 bf16 (4 VGPRs)
typedef __attribute__((ext_vector_type(4))) float float4_;  // 4 fp32 (MFMA C/D)
typedef __attribute__((ext_vector_type(2))) float float2_;  // packed fp32 (VOP3P)

// pack two fp32 -> bf16x2 (round-half-up: +0x8000 then take hi16; 3 VALU ops)
__device__ __forceinline__ int pack2_bf16(float a, float b) {
    union { float f; unsigned u; } ua, ub; ua.f = a; ub.f = b;
    unsigned ra = ua.u + 0x8000u;
    unsigned rb = ub.u + 0x8000u;
    return (int)__builtin_amdgcn_perm(rb, ra, 0x07060302);  // hi16(rb):hi16(ra)
}

__device__ __forceinline__ float2_ pk_fma(float2_ a, float2_ b, float2_ c) {
    return __builtin_elementwise_fma(a, b, c);              // -> v_pk_fma_f32
}
__device__ __forceinline__ float2_ pk_max0(float2_ a) {
    return __builtin_elementwise_max(a, (float2_){0.f, 0.f});  // -> v_pk_max_f32
}

// MFMA 16x16x32 bf16 layouts (HW-verified R4/R5):
//   A[m][k]: m=lane&15, k=(lane>>4)*8+j ; B[k][n]: n=lane&15, k=(lane>>4)*8+j
//   D[m][n]: m=(lane>>4)*4+reg, n=lane&15
// Transposed trick (R5): D2 = mfma(W2^T, h1) -> lane holds h2^T rows
// j2=quad*4+reg (+16 for second MFMA) for its own sample row n=lane&15.
__global__ __launch_bounds__(256, 4)
void ode_rk4_mfma(const float* __restrict__ x,
                  const float* __restrict__ samples,
                  const float* __restrict__ w1, const float* __restrict__ b1,
                  const float* __restrict__ w2, const float* __restrict__ b2,
                  const float* __restrict__ w3, const float* __restrict__ b3,
                  const float* __restrict__ w_out, const float* __restrict__ b_out,
                  float* __restrict__ out, int B)
{
    const int lane  = threadIdx.x & 63;
    const int w     = threadIdx.x >> 6;
    const int col16 = lane & 15;              // this lane's sample row (mod 16)
    const int quad  = lane >> 4;              // 0..3

    const int rowBase = (blockIdx.x * 4 + w) * 16;
    const int row = rowBase + col16;

    // ---- persistent operands (built once; reused 1024 evals) ----
    // layer1 weights as float2 pairs, j = quad*8 + 2p / 2p+1
    float2_ w1a[4], w1b[4], w1c[4], b1l[4];
#pragma unroll
    for (int p = 0; p < 4; ++p) {
        int j = quad * 8 + 2 * p;
        w1a[p] = (float2_){w1[0 * 32 + j], w1[0 * 32 + j + 1]};
        w1b[p] = (float2_){w1[1 * 32 + j], w1[1 * 32 + j + 1]};
        w1c[p] = (float2_){w1[2 * 32 + j], w1[2 * 32 + j + 1]};
        b1l[p] = (float2_){b1[j], b1[j + 1]};
    }
    // W2^T A-frags: A[m=j2][k=i1] = w2[i1*32 + j2]; two j2 tiles
    short8 W2Ta, W2Tb;
#pragma unroll
    for (int jl = 0; jl < 8; ++jl) {
        int i1 = quad * 8 + jl;
        W2Ta[jl] = (short)(pack2_bf16(w2[i1 * 32 + col16], 0.f) & 0xffff);
        W2Tb[jl] = (short)(pack2_bf16(w2[i1 * 32 + col16 + 16], 0.f) & 0xffff);
    }
    float4_ Cb2a, Cb2b;
#pragma unroll
    for (int r = 0; r < 4; ++r) {
        Cb2a[r] = b2[quad * 4 + r];
        Cb2b[r] = b2[16 + quad * 4 + r];
    }
    // layer3 weights as float2 pairs over r: j2 = quad*4 + {2p,2p+1} (+16 for B)
    float2_ w3A[3][2], w3B[3][2];
#pragma unroll
    for (int d = 0; d < 3; ++d) {
#pragma unroll
        for (int p = 0; p < 2; ++p) {
            int jA = quad * 4 + 2 * p, jB = 16 + quad * 4 + 2 * p;
            w3A[d][p] = (float2_){w3[jA * 3 + d], w3[(jA + 1) * 3 + d]};
            w3B[d][p] = (float2_){w3[jB * 3 + d], w3[(jB + 1) * 3 + d]};
        }
    }

    // ---- scalars ----
    const float maxT = samples[7];
    const float dt   = maxT / 64.0f;
    const float dt2  = 0.5f * dt;
    const float dt6  = dt / 6.0f;

    int sidx[8];
#pragma unroll
    for (int j = 0; j < 8; ++j) {
        int id = (int)rintf(samples[j] / dt) - 1;   // jnp.round = RNE
        id = id < 0 ? 0 : (id > NSTEPS - 1 ? NSTEPS - 1 : id);
        sidx[j] = id;
    }
    const float wo0 = w_out[0], wo1 = w_out[1], wo2 = w_out[2];
    const float bo  = b_out[0];
    const float b30 = b3[0], b31 = b3[1], b32 = b3[2];

    // state: y0,y1 packed; y2 scalar
    float2_ y01 = (float2_){x[(size_t)row * 3 + 0], x[(size_t)row * 3 + 1]};
    float   y2  = x[(size_t)row * 3 + 2];

#pragma unroll 1
    for (int s = 0; s < NSTEPS; ++s) {
        float2_ acc01 = (float2_){0.f, 0.f};
        float   acc2  = 0.f;
        float2_ a01 = y01;
        float   a2  = y2;

#pragma unroll 1
        for (int st = 0; st < 4; ++st) {
            // ---- layer1 on packed VALU, result already in MFMA B-frag layout ----
            float2_ a0v = (float2_){a01.x, a01.x};
            float2_ a1v = (float2_){a01.y, a01.y};
            float2_ a2v = (float2_){a2, a2};
            float2_ hp[4];
#pragma unroll
            for (int p = 0; p < 4; ++p) {
                float2_ h = pk_fma(a2v, w1c[p], pk_fma(a1v, w1b[p], pk_fma(a0v, w1a[p], b1l[p])));
                hp[p] = pk_max0(h);
            }
            union { short8 s8; int i4[4]; } A2u;
#pragma unroll
            for (int p = 0; p < 4; ++p)
                A2u.i4[p] = pack2_bf16(hp[p].x, hp[p].y);

            // ---- layer2 transposed: h2^T lands row-local ----
            float4_ D20 = __builtin_amdgcn_mfma_f32_16x16x32_bf16(W2Ta, A2u.s8, Cb2a, 0, 0, 0);
            float4_ D21 = __builtin_amdgcn_mfma_f32_16x16x32_bf16(W2Tb, A2u.s8, Cb2b, 0, 0, 0);

            // ---- layer3 on packed VALU over this lane's 8 j2 rows ----
            float2_ hA0 = pk_max0((float2_){D20[0], D20[1]});
            float2_ hA1 = pk_max0((float2_){D20[2], D20[3]});
            float2_ hB0 = pk_max0((float2_){D21[0], D21[1]});
            float2_ hB1 = pk_max0((float2_){D21[2], D21[3]});
            float2_ P0 = pk_fma(hA0, w3A[0][0], pk_fma(hA1, w3A[0][1],
                         pk_fma(hB0, w3B[0][0], hB1 * w3B[0][1])));
            float2_ P1 = pk_fma(hA0, w3A[1][0], pk_fma(hA1, w3A[1][1],
                         pk_fma(hB0, w3B[1][0], hB1 * w3B[1][1])));
            float2_ P2 = pk_fma(hA0, w3A[2][0], pk_fma(hA1, w3A[2][1],
                         pk_fma(hB0, w3B[2][0], hB1 * w3B[2][1])));
            float p0 = P0.x + P0.y, p1 = P1.x + P1.y, p2 = P2.x + P2.y;

            // reduce across the 4 quads (lanes l, l^16, l^32, l^48 share a row)
            p0 += __shfl_xor(p0, 16); p1 += __shfl_xor(p1, 16); p2 += __shfl_xor(p2, 16);
            p0 += __shfl_xor(p0, 32); p1 += __shfl_xor(p1, 32); p2 += __shfl_xor(p2, 32);
            float2_ k01 = (float2_){p0 + b30, p1 + b31};
            float   k2  = p2 + b32;

            const float ca = (st == 1 || st == 2) ? 2.0f : 1.0f;
            float2_ cav = (float2_){ca, ca};
            acc01 = pk_fma(cav, k01, acc01);
            acc2  = fmaf(ca, k2, acc2);
            const float ci = (st == 2) ? dt : dt2;
            float2_ civ = (float2_){ci, ci};
            a01 = pk_fma(civ, k01, y01);
            a2  = fmaf(ci, k2, y2);
        }
        float2_ dt6v = (float2_){dt6, dt6};
        y01 = pk_fma(dt6v, acc01, y01);
        y2  = fmaf(dt6, acc2, y2);

        if (quad == 0) {
#pragma unroll
            for (int j = 0; j < 8; ++j) {
                if (sidx[j] == s) {
                    out[(size_t)j * B + row] = fmaf(y2, wo2, fmaf(y01.y, wo1, fmaf(y01.x, wo0, bo)));
                }
            }
        }
    }
}

extern "C" void kernel_launch(void* const* d_in, const int* in_sizes, int n_in,
                              void* d_out, int out_size, void* d_ws, size_t ws_size,
                              hipStream_t stream) {
    const float* x       = (const float*)d_in[0];
    const float* samples = (const float*)d_in[1];
    const float* w1      = (const float*)d_in[2];
    const float* b1      = (const float*)d_in[3];
    const float* w2      = (const float*)d_in[4];
    const float* b2      = (const float*)d_in[5];
    const float* w3      = (const float*)d_in[6];
    const float* b3      = (const float*)d_in[7];
    const float* w_out   = (const float*)d_in[8];
    const float* b_out   = (const float*)d_in[9];
    float* out = (float*)d_out;

    const int B = in_sizes[0] / 3;           // 131072
    const int rowsPerBlock = 64;             // 4 waves x 16 rows
    const int grid = (B + rowsPerBlock - 1) / rowsPerBlock;
    ode_rk4_mfma<<<grid, 256, 0, stream>>>(
        x, samples, w1, b1, w2, b2, w3, b3, w_out, b_out, out, B);
}

// Round 9
// 361.633 us; speedup vs baseline: 1.1221x; 1.1221x over previous
//
#include <hip/hip_runtime.h>

#define NSTEPS 64

typedef __attribute__((ext_vector_type(8))) short short8;      // 8 bf16 (4 VGPRs)
typedef __attribute__((ext_vector_type(4))) float float4_;     // 4 fp32 (MFMA C/D)
typedef __attribute__((ext_vector_type(2))) __fp16 half2_;     // packed f16 (matches builtin return)

// pack two fp32 -> bf16x2 (round-half-up: +0x8000 then hi16; 3 VALU ops)
__device__ __forceinline__ int pack2_bf16(float a, float b) {
    union { float f; unsigned u; } ua, ub; ua.f = a; ub.f = b;
    unsigned ra = ua.u + 0x8000u;
    unsigned rb = ub.u + 0x8000u;
    return (int)__builtin_amdgcn_perm(rb, ra, 0x07060302);  // hi16(rb):hi16(ra)
}

__device__ __forceinline__ half2_ relu_pk_f16(float a, float b) {
    half2_ h = __builtin_amdgcn_cvt_pkrtz(a, b);            // v_cvt_pkrtz_f16_f32
    return __builtin_elementwise_max(h, (half2_)(__fp16)0); // v_pk_max_f16
}

// MFMA 16x16x32 bf16 layouts (HW-verified R4/R5):
//   A[m][k]: m=lane&15, k=(lane>>4)*8+j ; B[k][n]: n=lane&15, k=(lane>>4)*8+j
//   D[m][n]: m=(lane>>4)*4+reg, n=lane&15
// Transposed trick (R5): D = mfma(W2^T, h1) -> lane holds h2^T rows
// j2 = quad*4+reg (+16 for 2nd MFMA) for its own sample col n=lane&15.
// R7: TWO independent 16-row groups per wave for ILP across stall points.
__global__ __launch_bounds__(256, 3)
void ode_rk4_mfma(const float* __restrict__ x,
                  const float* __restrict__ samples,
                  const float* __restrict__ w1, const float* __restrict__ b1,
                  const float* __restrict__ w2, const float* __restrict__ b2,
                  const float* __restrict__ w3, const float* __restrict__ b3,
                  const float* __restrict__ w_out, const float* __restrict__ b_out,
                  float* __restrict__ out, int B)
{
    const int lane  = threadIdx.x & 63;
    const int w     = threadIdx.x >> 6;
    const int col16 = lane & 15;
    const int quad  = lane >> 4;

    const int rowBase = (blockIdx.x * 4 + w) * 32;
    const int rA = rowBase + col16;          // group A row
    const int rB = rA + 16;                  // group B row

    // ---- persistent operands (built once; reused 1024 evals) ----
    float w1a[8], w1b[8], w1c[8], b1l[8];
#pragma unroll
    for (int jl = 0; jl < 8; ++jl) {
        int j = quad * 8 + jl;
        w1a[jl] = w1[0 * 32 + j];
        w1b[jl] = w1[1 * 32 + j];
        w1c[jl] = w1[2 * 32 + j];
        b1l[jl] = b1[j];
    }
    short8 W2Ta, W2Tb;   // W2^T A-frags: A[m=j2][k=i1] = w2[i1*32+j2]
#pragma unroll
    for (int jl = 0; jl < 8; ++jl) {
        int i1 = quad * 8 + jl;
        W2Ta[jl] = (short)(pack2_bf16(w2[i1 * 32 + col16], 0.f) & 0xffff);
        W2Tb[jl] = (short)(pack2_bf16(w2[i1 * 32 + col16 + 16], 0.f) & 0xffff);
    }
    float4_ Cb2a, Cb2b;  // bias C-frags
#pragma unroll
    for (int r = 0; r < 4; ++r) {
        Cb2a[r] = b2[quad * 4 + r];
        Cb2b[r] = b2[16 + quad * 4 + r];
    }
    // layer3 weights as f16 pairs matching h pairs (j2, j2+1):
    // p=0: quad*4+{0,1}; p=1: quad*4+{2,3}; p=2: 16+quad*4+{0,1}; p=3: 16+quad*4+{2,3}
    half2_ w3h[3][4];
#pragma unroll
    for (int d = 0; d < 3; ++d) {
#pragma unroll
        for (int p = 0; p < 4; ++p) {
            int j0 = ((p >> 1) ? 16 : 0) + quad * 4 + (p & 1) * 2;
            w3h[d][p] = (half2_){(__fp16)w3[j0 * 3 + d], (__fp16)w3[(j0 + 1) * 3 + d]};
        }
    }

    // ---- scalars ----
    const float maxT = samples[7];
    const float dt   = maxT / 64.0f;
    const float dt2  = 0.5f * dt;
    const float dt6  = dt / 6.0f;

    int sidx[8];
    unsigned long long smask = 0ull;
#pragma unroll
    for (int j = 0; j < 8; ++j) {
        int id = (int)rintf(samples[j] / dt) - 1;   // jnp.round = RNE
        id = id < 0 ? 0 : (id > NSTEPS - 1 ? NSTEPS - 1 : id);
        sidx[j] = id;
        smask |= 1ull << id;
    }
    const float wo0 = w_out[0], wo1 = w_out[1], wo2 = w_out[2];
    const float bo  = b_out[0];
    const float b30 = b3[0], b31 = b3[1], b32 = b3[2];

    float yA0 = x[(size_t)rA * 3 + 0], yA1 = x[(size_t)rA * 3 + 1], yA2 = x[(size_t)rA * 3 + 2];
    float yB0 = x[(size_t)rB * 3 + 0], yB1 = x[(size_t)rB * 3 + 1], yB2 = x[(size_t)rB * 3 + 2];

#pragma unroll 1
    for (int s = 0; s < NSTEPS; ++s) {
        float accA0 = 0.f, accA1 = 0.f, accA2 = 0.f;
        float accB0 = 0.f, accB1 = 0.f, accB2 = 0.f;
        float aA0 = yA0, aA1 = yA1, aA2 = yA2;
        float aB0 = yB0, aB1 = yB1, aB2 = yB2;

#pragma unroll 1
        for (int st = 0; st < 4; ++st) {
            // ---- layer1 on VALU, both groups (independent streams) ----
            float hfA[8], hfB[8];
#pragma unroll
            for (int jl = 0; jl < 8; ++jl) {
                hfA[jl] = fmaxf(fmaf(aA2, w1c[jl], fmaf(aA1, w1b[jl], fmaf(aA0, w1a[jl], b1l[jl]))), 0.f);
                hfB[jl] = fmaxf(fmaf(aB2, w1c[jl], fmaf(aB1, w1b[jl], fmaf(aB0, w1a[jl], b1l[jl]))), 0.f);
            }
            union { short8 s8; int i4[4]; } A2A, A2B;
#pragma unroll
            for (int p = 0; p < 4; ++p) {
                A2A.i4[p] = pack2_bf16(hfA[2 * p], hfA[2 * p + 1]);
                A2B.i4[p] = pack2_bf16(hfB[2 * p], hfB[2 * p + 1]);
            }

            // ---- layer2 transposed: 4 independent MFMAs ----
            float4_ DA0 = __builtin_amdgcn_mfma_f32_16x16x32_bf16(W2Ta, A2A.s8, Cb2a, 0, 0, 0);
            float4_ DA1 = __builtin_amdgcn_mfma_f32_16x16x32_bf16(W2Tb, A2A.s8, Cb2b, 0, 0, 0);
            float4_ DB0 = __builtin_amdgcn_mfma_f32_16x16x32_bf16(W2Ta, A2B.s8, Cb2a, 0, 0, 0);
            float4_ DB1 = __builtin_amdgcn_mfma_f32_16x16x32_bf16(W2Tb, A2B.s8, Cb2b, 0, 0, 0);

            // ---- relu -> packed f16 pairs ----
            half2_ hA[4], hB[4];
            hA[0] = relu_pk_f16(DA0[0], DA0[1]); hA[1] = relu_pk_f16(DA0[2], DA0[3]);
            hA[2] = relu_pk_f16(DA1[0], DA1[1]); hA[3] = relu_pk_f16(DA1[2], DA1[3]);
            hB[0] = relu_pk_f16(DB0[0], DB0[1]); hB[1] = relu_pk_f16(DB0[2], DB0[3]);
            hB[2] = relu_pk_f16(DB1[0], DB1[1]); hB[3] = relu_pk_f16(DB1[2], DB1[3]);

            // ---- layer3 via v_dot2_f32_f16 (12 dot2 per group) ----
            float pA0 = 0.f, pA1 = 0.f, pA2 = 0.f;
            float pB0 = 0.f, pB1 = 0.f, pB2 = 0.f;
#pragma unroll
            for (int p = 0; p < 4; ++p) {
                pA0 = __builtin_amdgcn_fdot2(hA[p], w3h[0][p], pA0, false);
                pA1 = __builtin_amdgcn_fdot2(hA[p], w3h[1][p], pA1, false);
                pA2 = __builtin_amdgcn_fdot2(hA[p], w3h[2][p], pA2, false);
                pB0 = __builtin_amdgcn_fdot2(hB[p], w3h[0][p], pB0, false);
                pB1 = __builtin_amdgcn_fdot2(hB[p], w3h[1][p], pB1, false);
                pB2 = __builtin_amdgcn_fdot2(hB[p], w3h[2][p], pB2, false);
            }

            // ---- reduce across the 4 quads (A and B chains interleave) ----
            pA0 += __shfl_xor(pA0, 16); pB0 += __shfl_xor(pB0, 16);
            pA1 += __shfl_xor(pA1, 16); pB1 += __shfl_xor(pB1, 16);
            pA2 += __shfl_xor(pA2, 16); pB2 += __shfl_xor(pB2, 16);
            pA0 += __shfl_xor(pA0, 32); pB0 += __shfl_xor(pB0, 32);
            pA1 += __shfl_xor(pA1, 32); pB1 += __shfl_xor(pB1, 32);
            pA2 += __shfl_xor(pA2, 32); pB2 += __shfl_xor(pB2, 32);
            float kA0 = pA0 + b30, kA1 = pA1 + b31, kA2 = pA2 + b32;
            float kB0 = pB0 + b30, kB1 = pB1 + b31, kB2 = pB2 + b32;

            const float ca = (st == 1 || st == 2) ? 2.0f : 1.0f;
            accA0 = fmaf(ca, kA0, accA0); accA1 = fmaf(ca, kA1, accA1); accA2 = fmaf(ca, kA2, accA2);
            accB0 = fmaf(ca, kB0, accB0); accB1 = fmaf(ca, kB1, accB1); accB2 = fmaf(ca, kB2, accB2);
            const float ci = (st == 2) ? dt : dt2;
            aA0 = fmaf(ci, kA0, yA0); aA1 = fmaf(ci, kA1, yA1); aA2 = fmaf(ci, kA2, yA2);
            aB0 = fmaf(ci, kB0, yB0); aB1 = fmaf(ci, kB1, yB1); aB2 = fmaf(ci, kB2, yB2);
        }
        yA0 = fmaf(dt6, accA0, yA0); yA1 = fmaf(dt6, accA1, yA1); yA2 = fmaf(dt6, accA2, yA2);
        yB0 = fmaf(dt6, accB0, yB0); yB1 = fmaf(dt6, accB1, yB1); yB2 = fmaf(dt6, accB2, yB2);

        // wave-uniform SALU fast path: most steps store nothing
        if ((smask >> s) & 1ull) {
            if (quad == 0) {
#pragma unroll
                for (int j = 0; j < 8; ++j) {
                    if (sidx[j] == s) {
                        out[(size_t)j * B + rA] = fmaf(yA2, wo2, fmaf(yA1, wo1, fmaf(yA0, wo0, bo)));
                        out[(size_t)j * B + rB] = fmaf(yB2, wo2, fmaf(yB1, wo1, fmaf(yB0, wo0, bo)));
                    }
                }
            }
        }
    }
}

extern "C" void kernel_launch(void* const* d_in, const int* in_sizes, int n_in,
                              void* d_out, int out_size, void* d_ws, size_t ws_size,
                              hipStream_t stream) {
    const float* x       = (const float*)d_in[0];
    const float* samples = (const float*)d_in[1];
    const float* w1      = (const float*)d_in[2];
    const float* b1      = (const float*)d_in[3];
    const float* w2      = (const float*)d_in[4];
    const float* b2      = (const float*)d_in[5];
    const float* w3      = (const float*)d_in[6];
    const float* b3      = (const float*)d_in[7];
    const float* w_out   = (const float*)d_in[8];
    const float* b_out   = (const float*)d_in[9];
    float* out = (float*)d_out;

    const int B = in_sizes[0] / 3;           // 131072
    const int rowsPerBlock = 128;            // 4 waves x 32 rows (2 groups of 16)
    const int grid = (B + rowsPerBlock - 1) / rowsPerBlock;
    ode_rk4_mfma<<<grid, 256, 0, stream>>>(
        x, samples, w1, b1, w2, b2, w3, b3, w_out, b_out, out, B);
}

// Round 10
// 359.716 us; speedup vs baseline: 1.1281x; 1.0053x over previous
//
#include <hip/hip_runtime.h>

#define NSTEPS 64

typedef __attribute__((ext_vector_type(4))) float float4_;     // 4 fp32 (MFMA C/D)
typedef __attribute__((ext_vector_type(2))) __fp16 half2_;     // packed f16
typedef __attribute__((ext_vector_type(8))) __fp16 half8_;     // f16 MFMA A/B operand

__device__ __forceinline__ half2_ relu_pk_f16(float a, float b) {
    half2_ h = __builtin_amdgcn_cvt_pkrtz(a, b);               // v_cvt_pkrtz_f16_f32
    return __builtin_elementwise_max(h, (half2_)(__fp16)0);    // v_pk_max_f16
}

// MFMA 16x16x32 layouts (HW-verified R4/R5, dtype-independent per guide):
//   A[m][k]: m=lane&15, k=(lane>>4)*8+j ; B[k][n]: n=lane&15, k=(lane>>4)*8+j
//   D[m][n]: m=(lane>>4)*4+reg, n=lane&15
// Transposed trick (R5): D = mfma(W2^T, h1) -> lane holds h2^T rows
// j2 = quad*4+reg (+16 for 2nd MFMA) for its own sample col n=lane&15.
// R7: TWO independent 16-row groups per wave for ILP across stall points.
// R10: all-f16 datapath — L1 via fdot2 (bias folded), h1 stays f16, f16 MFMA.
__global__ __launch_bounds__(256, 4)
void ode_rk4_mfma(const float* __restrict__ x,
                  const float* __restrict__ samples,
                  const float* __restrict__ w1, const float* __restrict__ b1,
                  const float* __restrict__ w2, const float* __restrict__ b2,
                  const float* __restrict__ w3, const float* __restrict__ b3,
                  const float* __restrict__ w_out, const float* __restrict__ b_out,
                  float* __restrict__ out, int B)
{
    const int lane  = threadIdx.x & 63;
    const int w     = threadIdx.x >> 6;
    const int col16 = lane & 15;
    const int quad  = lane >> 4;

    const int rowBase = (blockIdx.x * 4 + w) * 32;
    const int rA = rowBase + col16;          // group A row
    const int rB = rA + 16;                  // group B row

    // ---- persistent operands (built once; reused 1024 evals) ----
    // layer1 weight pairs for fdot2: w1p = (w1[0][j], w1[1][j]), w1q = (w1[2][j], b1[j])
    half2_ w1p[8], w1q[8];
#pragma unroll
    for (int jl = 0; jl < 8; ++jl) {
        int j = quad * 8 + jl;
        w1p[jl] = (half2_){(__fp16)w1[0 * 32 + j], (__fp16)w1[1 * 32 + j]};
        w1q[jl] = (half2_){(__fp16)w1[2 * 32 + j], (__fp16)b1[j]};
    }
    // W2^T A-frags in f16: A[m=j2][k=i1] = w2[i1*32+j2]
    union { half2_ h2[4]; half8_ h8; } W2Ta, W2Tb;
#pragma unroll
    for (int p = 0; p < 4; ++p) {
        int i1 = quad * 8 + 2 * p;
        W2Ta.h2[p] = (half2_){(__fp16)w2[i1 * 32 + col16], (__fp16)w2[(i1 + 1) * 32 + col16]};
        W2Tb.h2[p] = (half2_){(__fp16)w2[i1 * 32 + col16 + 16], (__fp16)w2[(i1 + 1) * 32 + col16 + 16]};
    }
    float4_ Cb2a, Cb2b;  // bias C-frags
#pragma unroll
    for (int r = 0; r < 4; ++r) {
        Cb2a[r] = b2[quad * 4 + r];
        Cb2b[r] = b2[16 + quad * 4 + r];
    }
    // layer3 weights as f16 pairs matching h pairs (j2, j2+1)
    half2_ w3h[3][4];
#pragma unroll
    for (int d = 0; d < 3; ++d) {
#pragma unroll
        for (int p = 0; p < 4; ++p) {
            int j0 = ((p >> 1) ? 16 : 0) + quad * 4 + (p & 1) * 2;
            w3h[d][p] = (half2_){(__fp16)w3[j0 * 3 + d], (__fp16)w3[(j0 + 1) * 3 + d]};
        }
    }

    // ---- scalars ----
    const float maxT = samples[7];
    const float dt   = maxT / 64.0f;
    const float dt2  = 0.5f * dt;
    const float dt6  = dt / 6.0f;

    int sidx[8];
    unsigned long long smask = 0ull;
#pragma unroll
    for (int j = 0; j < 8; ++j) {
        int id = (int)rintf(samples[j] / dt) - 1;   // jnp.round = RNE
        id = id < 0 ? 0 : (id > NSTEPS - 1 ? NSTEPS - 1 : id);
        id = __builtin_amdgcn_readfirstlane(id);    // wave-uniform -> SGPR
        sidx[j] = id;
        smask |= 1ull << id;
    }
    const float wo0 = w_out[0], wo1 = w_out[1], wo2 = w_out[2];
    const float bo  = b_out[0];
    const float b30 = b3[0], b31 = b3[1], b32 = b3[2];

    float yA0 = x[(size_t)rA * 3 + 0], yA1 = x[(size_t)rA * 3 + 1], yA2 = x[(size_t)rA * 3 + 2];
    float yB0 = x[(size_t)rB * 3 + 0], yB1 = x[(size_t)rB * 3 + 1], yB2 = x[(size_t)rB * 3 + 2];

#pragma unroll 1
    for (int s = 0; s < NSTEPS; ++s) {
        float accA0 = 0.f, accA1 = 0.f, accA2 = 0.f;
        float accB0 = 0.f, accB1 = 0.f, accB2 = 0.f;
        float aA0 = yA0, aA1 = yA1, aA2 = yA2;
        float aB0 = yB0, aB1 = yB1, aB2 = yB2;

#pragma unroll 1
        for (int st = 0; st < 4; ++st) {
            // ---- layer1 via fdot2 (bias folded), both groups ----
            half2_ aA01 = __builtin_amdgcn_cvt_pkrtz(aA0, aA1);
            half2_ aA2o = __builtin_amdgcn_cvt_pkrtz(aA2, 1.0f);
            half2_ aB01 = __builtin_amdgcn_cvt_pkrtz(aB0, aB1);
            half2_ aB2o = __builtin_amdgcn_cvt_pkrtz(aB2, 1.0f);
            float hfA[8], hfB[8];
#pragma unroll
            for (int jl = 0; jl < 8; ++jl) {
                hfA[jl] = __builtin_amdgcn_fdot2(aA01, w1p[jl],
                          __builtin_amdgcn_fdot2(aA2o, w1q[jl], 0.f, false), false);
                hfB[jl] = __builtin_amdgcn_fdot2(aB01, w1p[jl],
                          __builtin_amdgcn_fdot2(aB2o, w1q[jl], 0.f, false), false);
            }
            union { half2_ h2[4]; half8_ h8; } A2A, A2B;
#pragma unroll
            for (int p = 0; p < 4; ++p) {
                A2A.h2[p] = relu_pk_f16(hfA[2 * p], hfA[2 * p + 1]);
                A2B.h2[p] = relu_pk_f16(hfB[2 * p], hfB[2 * p + 1]);
            }

            // ---- layer2 transposed: 4 independent f16 MFMAs ----
            float4_ DA0 = __builtin_amdgcn_mfma_f32_16x16x32_f16(W2Ta.h8, A2A.h8, Cb2a, 0, 0, 0);
            float4_ DA1 = __builtin_amdgcn_mfma_f32_16x16x32_f16(W2Tb.h8, A2A.h8, Cb2b, 0, 0, 0);
            float4_ DB0 = __builtin_amdgcn_mfma_f32_16x16x32_f16(W2Ta.h8, A2B.h8, Cb2a, 0, 0, 0);
            float4_ DB1 = __builtin_amdgcn_mfma_f32_16x16x32_f16(W2Tb.h8, A2B.h8, Cb2b, 0, 0, 0);

            // ---- relu -> packed f16 pairs ----
            half2_ hA[4], hB[4];
            hA[0] = relu_pk_f16(DA0[0], DA0[1]); hA[1] = relu_pk_f16(DA0[2], DA0[3]);
            hA[2] = relu_pk_f16(DA1[0], DA1[1]); hA[3] = relu_pk_f16(DA1[2], DA1[3]);
            hB[0] = relu_pk_f16(DB0[0], DB0[1]); hB[1] = relu_pk_f16(DB0[2], DB0[3]);
            hB[2] = relu_pk_f16(DB1[0], DB1[1]); hB[3] = relu_pk_f16(DB1[2], DB1[3]);

            // ---- layer3 via fdot2 (12 per group) ----
            float pA0 = 0.f, pA1 = 0.f, pA2 = 0.f;
            float pB0 = 0.f, pB1 = 0.f, pB2 = 0.f;
#pragma unroll
            for (int p = 0; p < 4; ++p) {
                pA0 = __builtin_amdgcn_fdot2(hA[p], w3h[0][p], pA0, false);
                pA1 = __builtin_amdgcn_fdot2(hA[p], w3h[1][p], pA1, false);
                pA2 = __builtin_amdgcn_fdot2(hA[p], w3h[2][p], pA2, false);
                pB0 = __builtin_amdgcn_fdot2(hB[p], w3h[0][p], pB0, false);
                pB1 = __builtin_amdgcn_fdot2(hB[p], w3h[1][p], pB1, false);
                pB2 = __builtin_amdgcn_fdot2(hB[p], w3h[2][p], pB2, false);
            }

            // ---- reduce across the 4 quads (A and B chains interleave) ----
            pA0 += __shfl_xor(pA0, 16); pB0 += __shfl_xor(pB0, 16);
            pA1 += __shfl_xor(pA1, 16); pB1 += __shfl_xor(pB1, 16);
            pA2 += __shfl_xor(pA2, 16); pB2 += __shfl_xor(pB2, 16);
            pA0 += __shfl_xor(pA0, 32); pB0 += __shfl_xor(pB0, 32);
            pA1 += __shfl_xor(pA1, 32); pB1 += __shfl_xor(pB1, 32);
            pA2 += __shfl_xor(pA2, 32); pB2 += __shfl_xor(pB2, 32);
            float kA0 = pA0 + b30, kA1 = pA1 + b31, kA2 = pA2 + b32;
            float kB0 = pB0 + b30, kB1 = pB1 + b31, kB2 = pB2 + b32;

            const float ca = (st == 1 || st == 2) ? 2.0f : 1.0f;
            accA0 = fmaf(ca, kA0, accA0); accA1 = fmaf(ca, kA1, accA1); accA2 = fmaf(ca, kA2, accA2);
            accB0 = fmaf(ca, kB0, accB0); accB1 = fmaf(ca, kB1, accB1); accB2 = fmaf(ca, kB2, accB2);
            const float ci = (st == 2) ? dt : dt2;
            aA0 = fmaf(ci, kA0, yA0); aA1 = fmaf(ci, kA1, yA1); aA2 = fmaf(ci, kA2, yA2);
            aB0 = fmaf(ci, kB0, yB0); aB1 = fmaf(ci, kB1, yB1); aB2 = fmaf(ci, kB2, yB2);
        }
        yA0 = fmaf(dt6, accA0, yA0); yA1 = fmaf(dt6, accA1, yA1); yA2 = fmaf(dt6, accA2, yA2);
        yB0 = fmaf(dt6, accB0, yB0); yB1 = fmaf(dt6, accB1, yB1); yB2 = fmaf(dt6, accB2, yB2);

        // wave-uniform SALU fast path: most steps store nothing
        if ((smask >> s) & 1ull) {
            if (quad == 0) {
#pragma unroll
                for (int j = 0; j < 8; ++j) {
                    if (sidx[j] == s) {
                        out[(size_t)j * B + rA] = fmaf(yA2, wo2, fmaf(yA1, wo1, fmaf(yA0, wo0, bo)));
                        out[(size_t)j * B + rB] = fmaf(yB2, wo2, fmaf(yB1, wo1, fmaf(yB0, wo0, bo)));
                    }
                }
            }
        }
    }
}

extern "C" void kernel_launch(void* const* d_in, const int* in_sizes, int n_in,
                              void* d_out, int out_size, void* d_ws, size_t ws_size,
                              hipStream_t stream) {
    const float* x       = (const float*)d_in[0];
    const float* samples = (const float*)d_in[1];
    const float* w1      = (const float*)d_in[2];
    const float* b1      = (const float*)d_in[3];
    const float* w2      = (const float*)d_in[4];
    const float* b2      = (const float*)d_in[5];
    const float* w3      = (const float*)d_in[6];
    const float* b3      = (const float*)d_in[7];
    const float* w_out   = (const float*)d_in[8];
    const float* b_out   = (const float*)d_in[9];
    float* out = (float*)d_out;

    const int B = in_sizes[0] / 3;           // 131072
    const int rowsPerBlock = 128;            // 4 waves x 32 rows (2 groups of 16)
    const int grid = (B + rowsPerBlock - 1) / rowsPerBlock;
    ode_rk4_mfma<<<grid, 256, 0, stream>>>(
        x, samples, w1, b1, w2, b2, w3, b3, w_out, b_out, out, B);
}